// Round 1
// baseline (42.938 us; speedup 1.0000x reference)
//
#include <hip/hip_runtime.h>

// x: [32, 256, 64, 64] f32, y: [32, 4] f32 -> out: [32, 260, 64, 64] f32
// Pure bandwidth op: copy x into channels [0,256), broadcast y[b][j] into
// channels [256,260). All in float4 units (H*W = 4096 divisible by 4).

#define B        32
#define HW4      1024u            /* 64*64/4 float4 per channel-plane  */
#define XC       256u             /* x channels                         */
#define YC       4u               /* y channels                         */
#define X_PER_B  (XC * HW4)       /* 262144 float4 of x per sample      */
#define O_PER_B  ((XC + YC) * HW4)/* 266240 float4 of out per sample    */

__global__ __launch_bounds__(256) void _Concat_61710090109042_kernel(
    const float4* __restrict__ x, const float* __restrict__ y,
    float4* __restrict__ out, unsigned int n4) {
  unsigned int i = blockIdx.x * blockDim.x + threadIdx.x;
  if (i >= n4) return;

  unsigned int b   = i / O_PER_B;
  unsigned int rem = i - b * O_PER_B;

  float4 v;
  if (rem < X_PER_B) {
    v = x[b * X_PER_B + rem];
  } else {
    unsigned int j = (rem - X_PER_B) >> 10;   // /HW4
    float s = y[b * YC + j];
    v = make_float4(s, s, s, s);
  }
  out[i] = v;
}

extern "C" void kernel_launch(void* const* d_in, const int* in_sizes, int n_in,
                              void* d_out, int out_size, void* d_ws, size_t ws_size,
                              hipStream_t stream) {
  const float4* x = (const float4*)d_in[0];
  const float*  y = (const float*)d_in[1];
  float4* out = (float4*)d_out;

  unsigned int n4 = (unsigned int)(out_size / 4);   // 8,519,680
  unsigned int block = 256;
  unsigned int grid = (n4 + block - 1) / block;
  _Concat_61710090109042_kernel<<<grid, block, 0, stream>>>(x, y, out, n4);
}